// Round 11
// baseline (1671.228 us; speedup 1.0000x reference)
//
#include <hip/hip_runtime.h>
#include <hip/hip_bf16.h>
#include <math.h>

// Problem constants
#define B_   32
#define S_   512
#define V_   30000
#define E_   300
#define H_   200
#define NH_  4
#define ENC_ 400
#define G4_  800     // 4*H
#define NEGV  (-1e9f)
#define SCALE_ 1000.0f

typedef _Float16 half2v __attribute__((ext_vector_type(2)));
typedef _Float16 f16x8  __attribute__((ext_vector_type(8)));
typedef float    f32x4  __attribute__((ext_vector_type(4)));

#if defined(__has_builtin)
#if __has_builtin(__builtin_amdgcn_fdot2)
#define FDOT2(a,b,c) __builtin_amdgcn_fdot2((a),(b),(c),false)
#endif
#endif
#ifndef FDOT2
#define FDOT2(a,b,c) fmaf((float)(a)[1],(float)(b)[1], fmaf((float)(a)[0],(float)(b)[0],(c)))
#endif

// ---- workspace layout (float offsets) ----
#define OF_QVEC  320000ull     // q_state @ W_q  [400]
#define OF_WKQ   320448ull     // wkq [400][4]
#define OF_THETA 322048ull     // scores [B][4][512]
#define OF_MU    387584ull     // mu     [B][4][512]
#define OF_HP    453120ull     // hp [B][4][400]
#define OF_LEN   504320ull     // lengths (int) [32]
#define OF_XWF   504384ull     // xW forward  [B*S][800]
#define OF_XWB   13611584ull   // xW backward (natural s order) [B*S][800]
#define OF_HF    26718784ull   // h_f [B*S][200]
#define OF_HB    29995584ull   // h_b [B*S][200]

// -------- lengths from mask (dtype auto-detect: u8 / i32 / i64) --------
__global__ void k_lengths(const void* __restrict__ mask, int* __restrict__ lengths) {
  int b = blockIdx.x, lane = threadIdx.x;
  const unsigned char* mb = (const unsigned char*)mask;
  int mode;
  if (mb[1] != 0) mode = 0;
  else if (((const int*)mask)[1] != 0) mode = 1;
  else mode = 2;
  int cnt = 0;
  for (int s = lane; s < S_; s += 64) {
    int v;
    if (mode == 0)      v = mb[b*S_ + s] ? 1 : 0;
    else if (mode == 1) v = ((const int*)mask)[b*S_ + s] ? 1 : 0;
    else                v = ((const long long*)mask)[b*S_ + s] ? 1 : 0;
    cnt += v;
  }
  for (int off = 32; off; off >>= 1) cnt += __shfl_xor(cnt, off);
  if (lane == 0) lengths[b] = cnt;
}

// -------- qvec = q_state @ W_q --------
__global__ void k_qvec(const float* __restrict__ qs, const float* __restrict__ Wq,
                       float* __restrict__ qvec) {
  __shared__ float qsl[ENC_];
  int t = threadIdx.x;
  if (t < ENC_) qsl[t] = qs[t];
  __syncthreads();
  if (t < ENC_) {
    float acc = 0.f;
    for (int i = 0; i < ENC_; ++i) acc += qsl[i] * Wq[(size_t)i*ENC_ + t];
    qvec[t] = acc;
  }
}

// -------- wkq[e][head] --------
__global__ void k_wkq(const float* __restrict__ Wk, const float* __restrict__ qvec,
                      float* __restrict__ wkq) {
  int t = threadIdx.x;
  int e = blockIdx.x*64 + (t >> 2);
  int head = t & 3;
  if (e < ENC_) {
    float acc = 0.f;
    const float* row = Wk + (size_t)e*ENC_ + head*100;
    const float* qv  = qvec + head*100;
    for (int d = 0; d < 100; ++d) acc += row[d]*qv[d];
    wkq[e*4 + head] = acc;
  }
}

// -------- input projections via fp16 MFMA (unchanged, passing) --------
__global__ __launch_bounds__(256) void k_gemm_mfma(
    const int* __restrict__ x, const float* __restrict__ emb,
    const float* __restrict__ wf, const float* __restrict__ wb,
    const float* __restrict__ bf, const float* __restrict__ bb,
    float* __restrict__ xWf, float* __restrict__ xWb)
{
  __shared__ int xid[128];
  __shared__ __align__(16) _Float16 sA[128][40];
  __shared__ __align__(16) _Float16 sB[64][40];
  const int t = threadIdx.x;
  const int row0 = blockIdx.x * 128;
  const int col0 = blockIdx.y * 64;
  if (t < 128) xid[t] = x[row0 + t];
  const int w = t >> 6, lane = t & 63;
  const int wr = w >> 1, wc = w & 1;
  f32x4 acc[4][2] = {};
  const int ar = t >> 1, ah = t & 1;
  const int bc = t >> 2, bq = t & 3;
  const int colg = col0 + bc;
  const float* wsrc = (colg < 800) ? (wf + (size_t)colg*300)
                                   : (wb + (size_t)(colg-800)*300);
  __syncthreads();
  const float* asrc = emb + (size_t)xid[ar]*300;
  for (int kc = 0; kc < 10; ++kc) {
    const int k0 = kc*32;
    {
      const int kb = k0 + ah*16;
      _Float16 tmp[16];
      if (kb + 15 < 300) {
        #pragma unroll
        for (int q = 0; q < 4; ++q) {
          float4 a = *(const float4*)(asrc + kb + 4*q);
          tmp[4*q]  =(_Float16)a.x; tmp[4*q+1]=(_Float16)a.y;
          tmp[4*q+2]=(_Float16)a.z; tmp[4*q+3]=(_Float16)a.w;
        }
      } else {
        #pragma unroll
        for (int i = 0; i < 16; ++i)
          tmp[i] = (_Float16)((kb+i < 300) ? asrc[kb+i] : 0.f);
      }
      *(f16x8*)&sA[ar][ah*16]   = *(f16x8*)&tmp[0];
      *(f16x8*)&sA[ar][ah*16+8] = *(f16x8*)&tmp[8];
    }
    {
      const int kb = k0 + bq*8;
      _Float16 tmp[8];
      if (kb + 7 < 300) {
        #pragma unroll
        for (int q = 0; q < 2; ++q) {
          float4 a = *(const float4*)(wsrc + kb + 4*q);
          tmp[4*q]  =(_Float16)a.x; tmp[4*q+1]=(_Float16)a.y;
          tmp[4*q+2]=(_Float16)a.z; tmp[4*q+3]=(_Float16)a.w;
        }
      } else {
        #pragma unroll
        for (int i = 0; i < 8; ++i)
          tmp[i] = (_Float16)((kb+i < 300) ? wsrc[kb+i] : 0.f);
      }
      *(f16x8*)&sB[bc][bq*8] = *(f16x8*)&tmp[0];
    }
    __syncthreads();
    const int fr = lane & 15, kg = lane >> 4;
    f16x8 b0 = *(const f16x8*)&sB[wc*32 + fr][kg*8];
    f16x8 b1 = *(const f16x8*)&sB[wc*32 + 16 + fr][kg*8];
    #pragma unroll
    for (int m = 0; m < 4; ++m) {
      f16x8 afrag = *(const f16x8*)&sA[wr*64 + m*16 + fr][kg*8];
      acc[m][0] = __builtin_amdgcn_mfma_f32_16x16x32_f16(afrag, b0, acc[m][0], 0,0,0);
      acc[m][1] = __builtin_amdgcn_mfma_f32_16x16x32_f16(afrag, b1, acc[m][1], 0,0,0);
    }
    __syncthreads();
  }
  const int crb = (lane >> 4) * 4, ccol = lane & 15;
  #pragma unroll
  for (int n = 0; n < 2; ++n) {
    int colg2 = col0 + wc*32 + n*16 + ccol;
    bool isF = colg2 < 800;
    int colo = isF ? colg2 : colg2 - 800;
    float bias = isF ? bf[colo] : bb[colo];
    float* dst = isF ? xWf : xWb;
    #pragma unroll
    for (int m = 0; m < 4; ++m) {
      int row = row0 + wr*64 + m*16 + crb;
      #pragma unroll
      for (int r = 0; r < 4; ++r)
        dst[(size_t)(row+r)*800 + colo] = acc[m][n][r] + bias;
    }
  }
}

// -------- fallback LSTM (round-4 v2, measured 678 us, known-good) --------
__global__ __launch_bounds__(1024) void k_lstm_v2(
    const float* __restrict__ xWf, const float* __restrict__ xWb,
    const float* __restrict__ whhf, const float* __restrict__ whhb,
    const int* __restrict__ lengths,
    float* __restrict__ h_f, float* __restrict__ h_b)
{
  const int bid = blockIdx.x;
  const int dir = bid >> 5, b = bid & 31;
  const float* __restrict__ xW  = dir ? xWb : xWf;
  const float* __restrict__ whh = dir ? whhb : whhf;
  float* __restrict__ hout      = dir ? h_b : h_f;
  const int len = lengths[b];
  const int t = threadIdx.x;
  const int active = (t < G4_);

  __shared__ __align__(16) _Float16 hbh[200];
  __shared__ float gact[G4_];

  half2v w[100];
  if (active) {
    const float* rp = whh + (size_t)t*H_;
    #pragma unroll
    for (int j = 0; j < 50; ++j) {
      float2 a = *(const float2*)(rp + 2*j);
      w[j] = half2v{(_Float16)a.x, (_Float16)a.y};
    }
    #pragma unroll
    for (int j = 0; j < 50; ++j) {
      float2 a = *(const float2*)(rp + 100 + 2*j);
      w[50+j] = half2v{(_Float16)a.x, (_Float16)a.y};
    }
  }
  if (t < 200) hbh[t] = (_Float16)0.f;
  float cst = 0.f;
  const float* xbase = xW + (size_t)b*S_*G4_;
  const int isTanh = (t >= 400) && (t < 600);
  __syncthreads();

  for (int step = 0; step < len; ++step) {
    const int pos = dir ? (len-1-step) : step;
    if (active) {
      float xv = xbase[(size_t)pos*G4_ + t];
      float a0 = 0.f, a1 = 0.f;
      #pragma unroll
      for (int j = 0; j < 12; ++j) {
        float4 h4 = *(const float4*)&hbh[8*j];
        a0 = FDOT2(w[4*j],   __builtin_bit_cast(half2v, h4.x), a0);
        a1 = FDOT2(w[4*j+1], __builtin_bit_cast(half2v, h4.y), a1);
        a0 = FDOT2(w[4*j+2], __builtin_bit_cast(half2v, h4.z), a0);
        a1 = FDOT2(w[4*j+3], __builtin_bit_cast(half2v, h4.w), a1);
      }
      {
        float2 h2 = *(const float2*)&hbh[96];
        a0 = FDOT2(w[48], __builtin_bit_cast(half2v, h2.x), a0);
        a1 = FDOT2(w[49], __builtin_bit_cast(half2v, h2.y), a1);
      }
      #pragma unroll
      for (int j = 0; j < 12; ++j) {
        float4 h4 = *(const float4*)&hbh[100 + 8*j];
        a0 = FDOT2(w[50+4*j],   __builtin_bit_cast(half2v, h4.x), a0);
        a1 = FDOT2(w[50+4*j+1], __builtin_bit_cast(half2v, h4.y), a1);
        a0 = FDOT2(w[50+4*j+2], __builtin_bit_cast(half2v, h4.z), a0);
        a1 = FDOT2(w[50+4*j+3], __builtin_bit_cast(half2v, h4.w), a1);
      }
      {
        float2 h2 = *(const float2*)&hbh[196];
        a0 = FDOT2(w[98], __builtin_bit_cast(half2v, h2.x), a0);
        a1 = FDOT2(w[99], __builtin_bit_cast(half2v, h2.y), a1);
      }
      float pre = a0 + a1 + xv;
      float act;
      if (isTanh) {
        float gc = fminf(fmaxf(pre, -10.f), 10.f);
        float e2 = __expf(2.f*gc);
        act = (e2-1.f)/(e2+1.f);
      } else {
        act = 1.f/(1.f+__expf(-pre));
      }
      gact[t] = act;
    }
    __syncthreads();
    if (t < 200) {
      float ig = gact[t], fg = gact[200+t], gg = gact[400+t], og = gact[600+t];
      cst = fg*cst + ig*gg;
      float cc = fminf(fmaxf(cst, -10.f), 10.f);
      float ec = __expf(2.f*cc);
      float hn = og*((ec-1.f)/(ec+1.f));
      hout[((size_t)b*S_ + pos)*H_ + t] = hn;
      hbh[t] = (_Float16)hn;
    }
    __syncthreads();
  }
}

// -------- MFMA LSTM, AGPR-pinned weights + explicit XDL hazard waits --------
// Round-10 structure (which allocated cleanly: gate passed, no scratch) with
// the ONE fix: each 7-MFMA chain is a single asm block with
//   s_nop 1   at entry  (VALU acc-zero-init -> MFMA SrcC wait states)
//   3x s_nop 7 at exit  (24 cyc >= worst-case MFMA D-write -> VALU/DS read
//                        wait states; the hazard recognizer cannot see into
//                        INLINEASM, so round 10's gact store read acc while
//                        the XDL pipe was still writing it -> absmax 0.047)
// Nops are inside the block so the compiler cannot move the D-read earlier.
__global__ __launch_bounds__(512, 1) void k_lstm_mfma(
    const float* __restrict__ xWf, const float* __restrict__ xWb,
    const float* __restrict__ whhf, const float* __restrict__ whhb,
    const int* __restrict__ lengths,
    float* __restrict__ h_f, float* __restrict__ h_b)
{
  const int bid = blockIdx.x;
  const int dir = bid >> 5, b = bid & 31;
  const float* __restrict__ xW  = dir ? xWb : xWf;
  const float* __restrict__ whh = dir ? whhb : whhf;
  float* __restrict__ hout      = dir ? h_b : h_f;
  const int len = lengths[b];
  const int t = threadIdx.x;
  const int w = t >> 6, lane = t & 63;
  const int c16 = lane & 15, kq = lane >> 4;

  __shared__ __align__(16) _Float16 hbh[224];   // h fp16, k padded 200->224 (pad = 0)
  __shared__ float gact[G4_];                   // raw gate preacts

  // ---- one-time B-frag preload, pinned to AGPRs immediately ----
  // frag f = 8i+w: col = 16f+c16, k = 32kf+8kq+j; zero outside (f<50, k<200).
  f16x8 bfrag[7][7];
  #pragma unroll
  for (int i = 0; i < 7; ++i) {
    const int f = 8*i + w;
    const bool fv = (f < 50);
    const float* wr = whh + (size_t)(fv ? (16*f + c16) : 0) * H_;
    #pragma unroll
    for (int kf = 0; kf < 7; ++kf) {
      f16x8 v;
      #pragma unroll
      for (int j = 0; j < 8; ++j) {
        const int k = 32*kf + 8*kq + j;
        v[j] = (_Float16)((fv && k < 200) ? wr[k] : 0.f);
      }
      bfrag[i][kf] = v;
      asm("" : "+a"(bfrag[i][kf]));   // pin into AGPRs now (frees VGPRs)
    }
  }

  for (int i = t; i < 224; i += 512) hbh[i] = (_Float16)0.f;
  float cst = 0.f;
  const float* xbase = xW + (size_t)b*S_*G4_;
  __syncthreads();

  for (int step = 0; step < len; ++step) {
    const int pos = dir ? (len-1-step) : step;
    // prefetch xW gate inputs for tail threads (consumed after barrier)
    float xi = 0.f, xf_ = 0.f, xg = 0.f, xo = 0.f;
    if (t < H_) {
      const float* xr = xbase + (size_t)pos*G4_ + t;
      xi = xr[0]; xf_ = xr[H_]; xg = xr[2*H_]; xo = xr[3*H_];
    }
    // A-frags: addr depends only on kq -> every A-row = h (multicast reads)
    f16x8 afr[7];
    #pragma unroll
    for (int kf = 0; kf < 7; ++kf)
      afr[kf] = *(const f16x8*)&hbh[32*kf + 8*kq];
    // MFMA chains per owned N-frag; B read straight from AGPRs.
    #pragma unroll
    for (int i = 0; i < 7; ++i) {
      const int f = 8*i + w;
      if (f < 50) {
        f32x4 acc = {0.f, 0.f, 0.f, 0.f};
        asm volatile(
          "s_nop 1\n\t"
          "v_mfma_f32_16x16x32_f16 %0, %1, %8, %0\n\t"
          "v_mfma_f32_16x16x32_f16 %0, %2, %9, %0\n\t"
          "v_mfma_f32_16x16x32_f16 %0, %3, %10, %0\n\t"
          "v_mfma_f32_16x16x32_f16 %0, %4, %11, %0\n\t"
          "v_mfma_f32_16x16x32_f16 %0, %5, %12, %0\n\t"
          "v_mfma_f32_16x16x32_f16 %0, %6, %13, %0\n\t"
          "v_mfma_f32_16x16x32_f16 %0, %7, %14, %0\n\t"
          "s_nop 7\n\t"
          "s_nop 7\n\t"
          "s_nop 7"
          : "+v"(acc)
          : "v"(afr[0]), "v"(afr[1]), "v"(afr[2]), "v"(afr[3]),
            "v"(afr[4]), "v"(afr[5]), "v"(afr[6]),
            "a"(bfrag[i][0]), "a"(bfrag[i][1]), "a"(bfrag[i][2]),
            "a"(bfrag[i][3]), "a"(bfrag[i][4]), "a"(bfrag[i][5]),
            "a"(bfrag[i][6]));
        if (lane < 16) gact[16*f + lane] = acc[0];
      }
    }
    __syncthreads();
    if (t < H_) {
      float gi = gact[t]        + xi;
      float gf = gact[H_ + t]   + xf_;
      float gg = gact[2*H_ + t] + xg;
      float go = gact[3*H_ + t] + xo;
      float ig = 1.f/(1.f+__expf(-gi));
      float fg = 1.f/(1.f+__expf(-gf));
      float og = 1.f/(1.f+__expf(-go));
      float ggc = fminf(fmaxf(gg, -10.f), 10.f);
      float eg = __expf(2.f*ggc);
      cst = fg*cst + ig*((eg-1.f)/(eg+1.f));
      float cc = fminf(fmaxf(cst, -10.f), 10.f);
      float ec = __expf(2.f*cc);
      float hn = og*((ec-1.f)/(ec+1.f));
      hout[((size_t)b*S_ + pos)*H_ + t] = hn;
      hbh[t] = (_Float16)hn;
    }
    __syncthreads();
  }
}

// -------- scores --------
__global__ __launch_bounds__(256) void k_scores(
    const float* __restrict__ hf, const float* __restrict__ hb,
    const float* __restrict__ wkq, const int* __restrict__ lengths,
    float* __restrict__ theta)
{
  int wid = blockIdx.x*4 + (threadIdx.x >> 6);
  int lane = threadIdx.x & 63;
  int b = wid >> 9, s = wid & 511;
  const float* hfr = hf + ((size_t)b*S_ + s)*H_;
  const float* hbr = hb + ((size_t)b*S_ + s)*H_;
  bool valid = s < lengths[b];
  float a0=0.f, a1=0.f, a2=0.f, a3=0.f;
  if (valid) {
    for (int e = lane; e < ENC_; e += 64) {
      float hv = (e < H_) ? hfr[e] : hbr[e-H_];
      float4 w = *(const float4*)(wkq + e*4);
      a0 += hv*w.x; a1 += hv*w.y; a2 += hv*w.z; a3 += hv*w.w;
    }
    for (int off = 32; off; off >>= 1) {
      a0 += __shfl_xor(a0, off); a1 += __shfl_xor(a1, off);
      a2 += __shfl_xor(a2, off); a3 += __shfl_xor(a3, off);
    }
  }
  if (lane == 0) {
    size_t base = (size_t)b*2048 + s;
    theta[base       ] = valid ? SCALE_*a0 : NEGV;
    theta[base +  512] = valid ? SCALE_*a1 : NEGV;
    theta[base + 1024] = valid ? SCALE_*a2 : NEGV;
    theta[base + 1536] = valid ? SCALE_*a3 : NEGV;
  }
}

// -------- sparseMAP budget projection --------
__global__ void k_sparsemap(const float* __restrict__ theta, const int* __restrict__ lengths,
                            float* __restrict__ mu) {
  int pid = blockIdx.x;
  int lane = threadIdx.x;
  const float* th = theta + (size_t)pid*512;
  float v[8];
  #pragma unroll
  for (int i = 0; i < 8; ++i) v[i] = th[i*64 + lane];
  float kf = rintf(0.2f * (float)lengths[pid >> 2]);
  float mn = v[0], mx = v[0];
  #pragma unroll
  for (int i = 1; i < 8; ++i) { mn = fminf(mn, v[i]); mx = fmaxf(mx, v[i]); }
  for (int off = 32; off; off >>= 1) {
    mn = fminf(mn, __shfl_xor(mn, off)); mx = fmaxf(mx, __shfl_xor(mx, off));
  }
  float lo = mn - 1.f, hi = mx;
  for (int it = 0; it < 60; ++it) {
    float mid = 0.5f*(lo + hi);
    float s = 0.f;
    #pragma unroll
    for (int i = 0; i < 8; ++i) s += fminf(fmaxf(v[i]-mid, 0.f), 1.f);
    for (int off = 32; off; off >>= 1) s += __shfl_xor(s, off);
    bool big = s > kf;
    lo = big ? mid : lo;
    hi = big ? hi : mid;
  }
  float tau0 = 0.5f*(lo + hi);
  float fs = 0.f, nU = 0.f, nS = 0.f;
  #pragma unroll
  for (int i = 0; i < 8; ++i) {
    float m0 = v[i] - tau0;
    if (m0 >= 1.f) nU += 1.f;
    else if (m0 > 0.f) { fs += v[i]; nS += 1.f; }
  }
  for (int off = 32; off; off >>= 1) {
    fs += __shfl_xor(fs, off); nU += __shfl_xor(nU, off); nS += __shfl_xor(nS, off);
  }
  float tau = (fs + nU - kf) / fmaxf(nS, 1.f);
  tau = (nS > 0.f) ? tau : tau0;
  float* mo = mu + (size_t)pid*512;
  #pragma unroll
  for (int i = 0; i < 8; ++i) mo[i*64 + lane] = fminf(fmaxf(v[i]-tau, 0.f), 1.f);
}

// -------- hp[b,head,e] = sum_s mu * h --------
__global__ __launch_bounds__(512) void k_hp(
    const float* __restrict__ mu, const float* __restrict__ hf,
    const float* __restrict__ hb, float* __restrict__ hp)
{
  __shared__ float mul[512];
  int pid = blockIdx.x, b = pid >> 2;
  int t = threadIdx.x;
  mul[t] = mu[(size_t)pid*512 + t];
  __syncthreads();
  if (t < ENC_) {
    const float* hsrc = (t < H_) ? (hf + t) : (hb + (t - H_));
    float acc = 0.f;
    for (int s = 0; s < 512; ++s) {
      float m = mul[s];
      if (m != 0.f) acc += m * hsrc[((size_t)b*S_ + s)*H_];
    }
    hp[(size_t)pid*ENC_ + t] = acc;
  }
}

// -------- head --------
__global__ __launch_bounds__(512) void k_head(
    const float* __restrict__ hp, const float* __restrict__ Wv,
    const float* __restrict__ Wout, const float* __restrict__ Wh,
    const float* __restrict__ bh, float* __restrict__ out)
{
  __shared__ float hpl[1600];
  __shared__ float ppl[ENC_];
  __shared__ float ojl[ENC_];
  __shared__ float red[512];
  int b = blockIdx.x, t = threadIdx.x;
  for (int i = t; i < 1600; i += 512) hpl[i] = hp[(size_t)b*1600 + i];
  __syncthreads();
  if (t < ENC_) {
    int head = t / 100;
    float acc = 0.f;
    for (int e = 0; e < ENC_; ++e) acc += hpl[head*ENC_ + e] * Wv[(size_t)e*ENC_ + t];
    ppl[t] = acc;
  }
  __syncthreads();
  if (t < ENC_) {
    float acc = 0.f;
    for (int c = 0; c < ENC_; ++c) acc += ppl[c] * Wout[(size_t)c*ENC_ + t];
    ojl[t] = acc;
  }
  __syncthreads();
  red[t] = (t < ENC_) ? ojl[t]*Wh[t] : 0.f;
  __syncthreads();
  for (int sft = 256; sft; sft >>= 1) {
    if (t < sft) red[t] += red[t+sft];
    __syncthreads();
  }
  if (t == 0) out[b] = 1.f/(1.f + expf(-(red[0] + bh[0])));
}

// -------- z --------
__global__ void k_z(const float* __restrict__ mu, const int* __restrict__ lengths,
                    float* __restrict__ out) {
  int idx = blockIdx.x*256 + threadIdx.x;
  int b = idx >> 9, s = idx & 511;
  float zz = 0.f;
  if (s < lengths[b]) {
    size_t base = (size_t)b*2048 + s;
    zz = 0.25f*(mu[base] + mu[base+512] + mu[base+1024] + mu[base+1536]);
  }
  out[32 + idx] = zz;
}

extern "C" void kernel_launch(void* const* d_in, const int* in_sizes, int n_in,
                              void* d_out, int out_size, void* d_ws, size_t ws_size,
                              hipStream_t stream) {
  const int*   x    = (const int*)d_in[0];
  const void*  mask = d_in[1];
  const float* emb  = (const float*)d_in[2];
  const float* wihf = (const float*)d_in[3];
  const float* whhf = (const float*)d_in[4];
  const float* bf   = (const float*)d_in[5];
  const float* wihb = (const float*)d_in[6];
  const float* whhb = (const float*)d_in[7];
  const float* bb   = (const float*)d_in[8];
  const float* qs   = (const float*)d_in[9];
  const float* Wq   = (const float*)d_in[10];
  const float* Wk   = (const float*)d_in[11];
  const float* Wv   = (const float*)d_in[12];
  const float* Wout = (const float*)d_in[13];
  const float* Wh   = (const float*)d_in[14];
  const float* bh   = (const float*)d_in[15];
  float* out = (float*)d_out;
  float* W = (float*)d_ws;
  int* lengths = (int*)(W + OF_LEN);

  // Gate: use the MFMA LSTM unless the compiler scratched substantially.
  // Host-only, deterministic, capture-safe.
  hipFuncAttributes fa{};
  bool use_mfma = false;
  if (hipFuncGetAttributes(&fa, (const void*)k_lstm_mfma) == hipSuccess)
    use_mfma = (fa.localSizeBytes <= 256);

  k_lengths<<<32, 64, 0, stream>>>(mask, lengths);
  k_qvec<<<1, 512, 0, stream>>>(qs, Wq, W+OF_QVEC);
  k_wkq<<<7, 256, 0, stream>>>(Wk, W+OF_QVEC, W+OF_WKQ);
  k_gemm_mfma<<<dim3(128, 25), 256, 0, stream>>>(x, emb, wihf, wihb, bf, bb,
                                                 W+OF_XWF, W+OF_XWB);
  if (use_mfma)
    k_lstm_mfma<<<64, 512, 0, stream>>>(W+OF_XWF, W+OF_XWB, whhf, whhb,
                                        lengths, W+OF_HF, W+OF_HB);
  else
    k_lstm_v2<<<64, 1024, 0, stream>>>(W+OF_XWF, W+OF_XWB, whhf, whhb,
                                       lengths, W+OF_HF, W+OF_HB);
  k_scores<<<4096, 256, 0, stream>>>(W+OF_HF, W+OF_HB, W+OF_WKQ, lengths, W+OF_THETA);
  k_sparsemap<<<128, 64, 0, stream>>>(W+OF_THETA, lengths, W+OF_MU);
  k_hp<<<128, 512, 0, stream>>>(W+OF_MU, W+OF_HF, W+OF_HB, W+OF_HP);
  k_head<<<32, 512, 0, stream>>>(W+OF_HP, Wv, Wout, Wh, bh, out);
  k_z<<<64, 256, 0, stream>>>(W+OF_MU, lengths, out);
}

// Round 12
// 875.874 us; speedup vs baseline: 1.9081x; 1.9081x over previous
//
#include <hip/hip_runtime.h>
#include <hip/hip_bf16.h>
#include <math.h>

// Problem constants
#define B_   32
#define S_   512
#define V_   30000
#define E_   300
#define H_   200
#define NH_  4
#define ENC_ 400
#define G4_  800     // 4*H
#define NEGV  (-1e9f)
#define SCALE_ 1000.0f

typedef _Float16 half2v __attribute__((ext_vector_type(2)));
typedef _Float16 f16x8  __attribute__((ext_vector_type(8)));
typedef float    f32x4  __attribute__((ext_vector_type(4)));

#if defined(__has_builtin)
#if __has_builtin(__builtin_amdgcn_fdot2)
#define FDOT2(a,b,c) __builtin_amdgcn_fdot2((a),(b),(c),false)
#endif
#endif
#ifndef FDOT2
#define FDOT2(a,b,c) fmaf((float)(a)[1],(float)(b)[1], fmaf((float)(a)[0],(float)(b)[0],(c)))
#endif

// ---- workspace layout (float offsets) ----
#define OF_QVEC  320000ull     // q_state @ W_q  [400]
#define OF_WKQ   320448ull     // wkq [400][4]
#define OF_THETA 322048ull     // scores [B][4][512]
#define OF_MU    387584ull     // mu     [B][4][512]
#define OF_HP    453120ull     // hp [B][4][400]
#define OF_LEN   504320ull     // lengths (int) [32]
#define OF_XWF   504384ull     // xW forward  [B*S][800]
#define OF_XWB   13611584ull   // xW backward (natural s order) [B*S][800]
#define OF_HF    26718784ull   // h_f [B*S][200]
#define OF_HB    29995584ull   // h_b [B*S][200]

// -------- lengths from mask (dtype auto-detect: u8 / i32 / i64) --------
__global__ void k_lengths(const void* __restrict__ mask, int* __restrict__ lengths) {
  int b = blockIdx.x, lane = threadIdx.x;
  const unsigned char* mb = (const unsigned char*)mask;
  int mode;
  if (mb[1] != 0) mode = 0;
  else if (((const int*)mask)[1] != 0) mode = 1;
  else mode = 2;
  int cnt = 0;
  for (int s = lane; s < S_; s += 64) {
    int v;
    if (mode == 0)      v = mb[b*S_ + s] ? 1 : 0;
    else if (mode == 1) v = ((const int*)mask)[b*S_ + s] ? 1 : 0;
    else                v = ((const long long*)mask)[b*S_ + s] ? 1 : 0;
    cnt += v;
  }
  for (int off = 32; off; off >>= 1) cnt += __shfl_xor(cnt, off);
  if (lane == 0) lengths[b] = cnt;
}

// -------- qvec = q_state @ W_q --------
__global__ void k_qvec(const float* __restrict__ qs, const float* __restrict__ Wq,
                       float* __restrict__ qvec) {
  __shared__ float qsl[ENC_];
  int t = threadIdx.x;
  if (t < ENC_) qsl[t] = qs[t];
  __syncthreads();
  if (t < ENC_) {
    float acc = 0.f;
    for (int i = 0; i < ENC_; ++i) acc += qsl[i] * Wq[(size_t)i*ENC_ + t];
    qvec[t] = acc;
  }
}

// -------- wkq[e][head] --------
__global__ void k_wkq(const float* __restrict__ Wk, const float* __restrict__ qvec,
                      float* __restrict__ wkq) {
  int t = threadIdx.x;
  int e = blockIdx.x*64 + (t >> 2);
  int head = t & 3;
  if (e < ENC_) {
    float acc = 0.f;
    const float* row = Wk + (size_t)e*ENC_ + head*100;
    const float* qv  = qvec + head*100;
    for (int d = 0; d < 100; ++d) acc += row[d]*qv[d];
    wkq[e*4 + head] = acc;
  }
}

// -------- input projections via fp16 MFMA (builtins only; passing) --------
__global__ __launch_bounds__(256) void k_gemm_mfma(
    const int* __restrict__ x, const float* __restrict__ emb,
    const float* __restrict__ wf, const float* __restrict__ wb,
    const float* __restrict__ bf, const float* __restrict__ bb,
    float* __restrict__ xWf, float* __restrict__ xWb)
{
  __shared__ int xid[128];
  __shared__ __align__(16) _Float16 sA[128][40];
  __shared__ __align__(16) _Float16 sB[64][40];
  const int t = threadIdx.x;
  const int row0 = blockIdx.x * 128;
  const int col0 = blockIdx.y * 64;
  if (t < 128) xid[t] = x[row0 + t];
  const int w = t >> 6, lane = t & 63;
  const int wr = w >> 1, wc = w & 1;
  f32x4 acc[4][2] = {};
  const int ar = t >> 1, ah = t & 1;
  const int bc = t >> 2, bq = t & 3;
  const int colg = col0 + bc;
  const float* wsrc = (colg < 800) ? (wf + (size_t)colg*300)
                                   : (wb + (size_t)(colg-800)*300);
  __syncthreads();
  const float* asrc = emb + (size_t)xid[ar]*300;
  for (int kc = 0; kc < 10; ++kc) {
    const int k0 = kc*32;
    {
      const int kb = k0 + ah*16;
      _Float16 tmp[16];
      if (kb + 15 < 300) {
        #pragma unroll
        for (int q = 0; q < 4; ++q) {
          float4 a = *(const float4*)(asrc + kb + 4*q);
          tmp[4*q]  =(_Float16)a.x; tmp[4*q+1]=(_Float16)a.y;
          tmp[4*q+2]=(_Float16)a.z; tmp[4*q+3]=(_Float16)a.w;
        }
      } else {
        #pragma unroll
        for (int i = 0; i < 16; ++i)
          tmp[i] = (_Float16)((kb+i < 300) ? asrc[kb+i] : 0.f);
      }
      *(f16x8*)&sA[ar][ah*16]   = *(f16x8*)&tmp[0];
      *(f16x8*)&sA[ar][ah*16+8] = *(f16x8*)&tmp[8];
    }
    {
      const int kb = k0 + bq*8;
      _Float16 tmp[8];
      if (kb + 7 < 300) {
        #pragma unroll
        for (int q = 0; q < 2; ++q) {
          float4 a = *(const float4*)(wsrc + kb + 4*q);
          tmp[4*q]  =(_Float16)a.x; tmp[4*q+1]=(_Float16)a.y;
          tmp[4*q+2]=(_Float16)a.z; tmp[4*q+3]=(_Float16)a.w;
        }
      } else {
        #pragma unroll
        for (int i = 0; i < 8; ++i)
          tmp[i] = (_Float16)((kb+i < 300) ? wsrc[kb+i] : 0.f);
      }
      *(f16x8*)&sB[bc][bq*8] = *(f16x8*)&tmp[0];
    }
    __syncthreads();
    const int fr = lane & 15, kg = lane >> 4;
    f16x8 b0 = *(const f16x8*)&sB[wc*32 + fr][kg*8];
    f16x8 b1 = *(const f16x8*)&sB[wc*32 + 16 + fr][kg*8];
    #pragma unroll
    for (int m = 0; m < 4; ++m) {
      f16x8 afrag = *(const f16x8*)&sA[wr*64 + m*16 + fr][kg*8];
      acc[m][0] = __builtin_amdgcn_mfma_f32_16x16x32_f16(afrag, b0, acc[m][0], 0,0,0);
      acc[m][1] = __builtin_amdgcn_mfma_f32_16x16x32_f16(afrag, b1, acc[m][1], 0,0,0);
    }
    __syncthreads();
  }
  const int crb = (lane >> 4) * 4, ccol = lane & 15;
  #pragma unroll
  for (int n = 0; n < 2; ++n) {
    int colg2 = col0 + wc*32 + n*16 + ccol;
    bool isF = colg2 < 800;
    int colo = isF ? colg2 : colg2 - 800;
    float bias = isF ? bf[colo] : bb[colo];
    float* dst = isF ? xWf : xWb;
    #pragma unroll
    for (int m = 0; m < 4; ++m) {
      int row = row0 + wr*64 + m*16 + crb;
      #pragma unroll
      for (int r = 0; r < 4; ++r)
        dst[(size_t)(row+r)*800 + colo] = acc[m][n][r] + bias;
    }
  }
}

// -------- fallback LSTM (round-4 v2, measured 678 us, known-good) --------
__global__ __launch_bounds__(1024) void k_lstm_v2(
    const float* __restrict__ xWf, const float* __restrict__ xWb,
    const float* __restrict__ whhf, const float* __restrict__ whhb,
    const int* __restrict__ lengths,
    float* __restrict__ h_f, float* __restrict__ h_b)
{
  const int bid = blockIdx.x;
  const int dir = bid >> 5, b = bid & 31;
  const float* __restrict__ xW  = dir ? xWb : xWf;
  const float* __restrict__ whh = dir ? whhb : whhf;
  float* __restrict__ hout      = dir ? h_b : h_f;
  const int len = lengths[b];
  const int t = threadIdx.x;
  const int active = (t < G4_);

  __shared__ __align__(16) _Float16 hbh[200];
  __shared__ float gact[G4_];

  half2v w[100];
  if (active) {
    const float* rp = whh + (size_t)t*H_;
    #pragma unroll
    for (int j = 0; j < 50; ++j) {
      float2 a = *(const float2*)(rp + 2*j);
      w[j] = half2v{(_Float16)a.x, (_Float16)a.y};
    }
    #pragma unroll
    for (int j = 0; j < 50; ++j) {
      float2 a = *(const float2*)(rp + 100 + 2*j);
      w[50+j] = half2v{(_Float16)a.x, (_Float16)a.y};
    }
  }
  if (t < 200) hbh[t] = (_Float16)0.f;
  float cst = 0.f;
  const float* xbase = xW + (size_t)b*S_*G4_;
  const int isTanh = (t >= 400) && (t < 600);
  __syncthreads();

  for (int step = 0; step < len; ++step) {
    const int pos = dir ? (len-1-step) : step;
    if (active) {
      float xv = xbase[(size_t)pos*G4_ + t];
      float a0 = 0.f, a1 = 0.f;
      #pragma unroll
      for (int j = 0; j < 12; ++j) {
        float4 h4 = *(const float4*)&hbh[8*j];
        a0 = FDOT2(w[4*j],   __builtin_bit_cast(half2v, h4.x), a0);
        a1 = FDOT2(w[4*j+1], __builtin_bit_cast(half2v, h4.y), a1);
        a0 = FDOT2(w[4*j+2], __builtin_bit_cast(half2v, h4.z), a0);
        a1 = FDOT2(w[4*j+3], __builtin_bit_cast(half2v, h4.w), a1);
      }
      {
        float2 h2 = *(const float2*)&hbh[96];
        a0 = FDOT2(w[48], __builtin_bit_cast(half2v, h2.x), a0);
        a1 = FDOT2(w[49], __builtin_bit_cast(half2v, h2.y), a1);
      }
      #pragma unroll
      for (int j = 0; j < 12; ++j) {
        float4 h4 = *(const float4*)&hbh[100 + 8*j];
        a0 = FDOT2(w[50+4*j],   __builtin_bit_cast(half2v, h4.x), a0);
        a1 = FDOT2(w[50+4*j+1], __builtin_bit_cast(half2v, h4.y), a1);
        a0 = FDOT2(w[50+4*j+2], __builtin_bit_cast(half2v, h4.z), a0);
        a1 = FDOT2(w[50+4*j+3], __builtin_bit_cast(half2v, h4.w), a1);
      }
      {
        float2 h2 = *(const float2*)&hbh[196];
        a0 = FDOT2(w[98], __builtin_bit_cast(half2v, h2.x), a0);
        a1 = FDOT2(w[99], __builtin_bit_cast(half2v, h2.y), a1);
      }
      float pre = a0 + a1 + xv;
      float act;
      if (isTanh) {
        float gc = fminf(fmaxf(pre, -10.f), 10.f);
        float e2 = __expf(2.f*gc);
        act = (e2-1.f)/(e2+1.f);
      } else {
        act = 1.f/(1.f+__expf(-pre));
      }
      gact[t] = act;
    }
    __syncthreads();
    if (t < 200) {
      float ig = gact[t], fg = gact[200+t], gg = gact[400+t], og = gact[600+t];
      cst = fg*cst + ig*gg;
      float cc = fminf(fmaxf(cst, -10.f), 10.f);
      float ec = __expf(2.f*cc);
      float hn = og*((ec-1.f)/(ec+1.f));
      hout[((size_t)b*S_ + pos)*H_ + t] = hn;
      hbh[t] = (_Float16)hn;
    }
    __syncthreads();
  }
}

// -------- LSTM v2b: 512 threads, AGPR-pinned weights, zero spill --------
// 64 WGs x 512 thr (8 waves; launch_bounds(512,1) -> 2 waves/SIMD -> 256
// unified regs/wave). Thread t owns row t (all t) and row 512+t (t<288):
// 200 half2 weight regs, asm-"a"-pinned into the AGPR half of the unified
// file (the pin is the ONLY mechanism the allocator has honored across
// rounds 5-11: it cannot spill asm-constrained values). Working set ~30
// arch VGPRs. Per step: 25 uniform ds_read_b128 of h (200 fp16 = exactly
// 25x8, no tail) -> 200 fdot2 -> own-row nonlinearity -> gact -> barrier
// -> t<200 tail: c/h update, publish h -> barrier. vs v2 (1024 thr):
// HALF the per-CU LDS broadcast traffic (208 vs 416 wave-reads/step) and
// no scratch. Structure identical to the twice-validated v2 numerics.
__global__ __launch_bounds__(512, 1) void k_lstm_v2b(
    const float* __restrict__ xWf, const float* __restrict__ xWb,
    const float* __restrict__ whhf, const float* __restrict__ whhb,
    const int* __restrict__ lengths,
    float* __restrict__ h_f, float* __restrict__ h_b)
{
  const int bid = blockIdx.x;
  const int dir = bid >> 5, b = bid & 31;
  const float* __restrict__ xW  = dir ? xWb : xWf;
  const float* __restrict__ whh = dir ? whhb : whhf;
  float* __restrict__ hout      = dir ? h_b : h_f;
  const int len = lengths[b];
  const int t = threadIdx.x;
  const int row0 = t;                       // 0..511
  const bool has2 = (t < 288);
  const int row1 = has2 ? (512 + t) : 799;  // clamped for safe addressing

  __shared__ __align__(16) _Float16 hbh[200];
  __shared__ float gact[G4_];

  // ---- one-time weight preload: w0/w1[m] = W[row][2m..2m+1], pinned ----
  half2v w0[100], w1[100];
  {
    const float* r0 = whh + (size_t)row0*H_;
    const float* r1 = whh + (size_t)row1*H_;
    #pragma unroll
    for (int j = 0; j < 100; ++j) {
      float2 a = *(const float2*)(r0 + 2*j);
      w0[j] = half2v{(_Float16)a.x, (_Float16)a.y};
      float2 c = *(const float2*)(r1 + 2*j);
      w1[j] = half2v{(_Float16)c.x, (_Float16)c.y};
    }
    #pragma unroll
    for (int j = 0; j < 100; ++j) {
      asm("" : "+a"(w0[j]));   // pin to AGPR: allocator cannot spill these
      asm("" : "+a"(w1[j]));
    }
  }

  if (t < 200) hbh[t] = (_Float16)0.f;
  float cst = 0.f;
  const float* xbase = xW + (size_t)b*S_*G4_;
  const int isTanh0 = (row0 >= 400);               // row0 <= 511 < 600
  const int isTanh1 = (row1 >= 400) && (row1 < 600);
  __syncthreads();

  for (int step = 0; step < len; ++step) {
    const int pos = dir ? (len-1-step) : step;
    const float* xr = xbase + (size_t)pos*G4_;
    float xv0 = xr[row0];                          // coalesced over 512
    float xv1 = has2 ? xr[row1] : 0.f;             // coalesced over 288
    float a0 = 0.f, a1 = 0.f;
    #pragma unroll
    for (int j = 0; j < 25; ++j) {                 // h: 25 x b128, k = 8j..8j+7
      float4 h4 = *(const float4*)&hbh[8*j];
      half2v p0 = __builtin_bit_cast(half2v, h4.x);
      half2v p1 = __builtin_bit_cast(half2v, h4.y);
      half2v p2 = __builtin_bit_cast(half2v, h4.z);
      half2v p3 = __builtin_bit_cast(half2v, h4.w);
      a0 = FDOT2(w0[4*j],   p0, a0);
      a0 = FDOT2(w0[4*j+1], p1, a0);
      a0 = FDOT2(w0[4*j+2], p2, a0);
      a0 = FDOT2(w0[4*j+3], p3, a0);
      a1 = FDOT2(w1[4*j],   p0, a1);
      a1 = FDOT2(w1[4*j+1], p1, a1);
      a1 = FDOT2(w1[4*j+2], p2, a1);
      a1 = FDOT2(w1[4*j+3], p3, a1);
    }
    {
      float pre = a0 + xv0;
      float act;
      if (isTanh0) {
        float gc = fminf(fmaxf(pre, -10.f), 10.f);
        float e2 = __expf(2.f*gc);
        act = (e2-1.f)/(e2+1.f);
      } else {
        act = 1.f/(1.f+__expf(-pre));
      }
      gact[row0] = act;
    }
    if (has2) {
      float pre = a1 + xv1;
      float act;
      if (isTanh1) {
        float gc = fminf(fmaxf(pre, -10.f), 10.f);
        float e2 = __expf(2.f*gc);
        act = (e2-1.f)/(e2+1.f);
      } else {
        act = 1.f/(1.f+__expf(-pre));
      }
      gact[row1] = act;
    }
    __syncthreads();
    if (t < H_) {
      float ig = gact[t], fg = gact[H_+t], gg = gact[2*H_+t], og = gact[3*H_+t];
      cst = fg*cst + ig*gg;
      float cc = fminf(fmaxf(cst, -10.f), 10.f);
      float ec = __expf(2.f*cc);
      float hn = og*((ec-1.f)/(ec+1.f));
      hout[((size_t)b*S_ + pos)*H_ + t] = hn;
      hbh[t] = (_Float16)hn;
    }
    __syncthreads();
  }
}

// -------- scores --------
__global__ __launch_bounds__(256) void k_scores(
    const float* __restrict__ hf, const float* __restrict__ hb,
    const float* __restrict__ wkq, const int* __restrict__ lengths,
    float* __restrict__ theta)
{
  int wid = blockIdx.x*4 + (threadIdx.x >> 6);
  int lane = threadIdx.x & 63;
  int b = wid >> 9, s = wid & 511;
  const float* hfr = hf + ((size_t)b*S_ + s)*H_;
  const float* hbr = hb + ((size_t)b*S_ + s)*H_;
  bool valid = s < lengths[b];
  float a0=0.f, a1=0.f, a2=0.f, a3=0.f;
  if (valid) {
    for (int e = lane; e < ENC_; e += 64) {
      float hv = (e < H_) ? hfr[e] : hbr[e-H_];
      float4 w = *(const float4*)(wkq + e*4);
      a0 += hv*w.x; a1 += hv*w.y; a2 += hv*w.z; a3 += hv*w.w;
    }
    for (int off = 32; off; off >>= 1) {
      a0 += __shfl_xor(a0, off); a1 += __shfl_xor(a1, off);
      a2 += __shfl_xor(a2, off); a3 += __shfl_xor(a3, off);
    }
  }
  if (lane == 0) {
    size_t base = (size_t)b*2048 + s;
    theta[base       ] = valid ? SCALE_*a0 : NEGV;
    theta[base +  512] = valid ? SCALE_*a1 : NEGV;
    theta[base + 1024] = valid ? SCALE_*a2 : NEGV;
    theta[base + 1536] = valid ? SCALE_*a3 : NEGV;
  }
}

// -------- sparseMAP budget projection --------
__global__ void k_sparsemap(const float* __restrict__ theta, const int* __restrict__ lengths,
                            float* __restrict__ mu) {
  int pid = blockIdx.x;
  int lane = threadIdx.x;
  const float* th = theta + (size_t)pid*512;
  float v[8];
  #pragma unroll
  for (int i = 0; i < 8; ++i) v[i] = th[i*64 + lane];
  float kf = rintf(0.2f * (float)lengths[pid >> 2]);
  float mn = v[0], mx = v[0];
  #pragma unroll
  for (int i = 1; i < 8; ++i) { mn = fminf(mn, v[i]); mx = fmaxf(mx, v[i]); }
  for (int off = 32; off; off >>= 1) {
    mn = fminf(mn, __shfl_xor(mn, off)); mx = fmaxf(mx, __shfl_xor(mx, off));
  }
  float lo = mn - 1.f, hi = mx;
  for (int it = 0; it < 60; ++it) {
    float mid = 0.5f*(lo + hi);
    float s = 0.f;
    #pragma unroll
    for (int i = 0; i < 8; ++i) s += fminf(fmaxf(v[i]-mid, 0.f), 1.f);
    for (int off = 32; off; off >>= 1) s += __shfl_xor(s, off);
    bool big = s > kf;
    lo = big ? mid : lo;
    hi = big ? hi : mid;
  }
  float tau0 = 0.5f*(lo + hi);
  float fs = 0.f, nU = 0.f, nS = 0.f;
  #pragma unroll
  for (int i = 0; i < 8; ++i) {
    float m0 = v[i] - tau0;
    if (m0 >= 1.f) nU += 1.f;
    else if (m0 > 0.f) { fs += v[i]; nS += 1.f; }
  }
  for (int off = 32; off; off >>= 1) {
    fs += __shfl_xor(fs, off); nU += __shfl_xor(nU, off); nS += __shfl_xor(nS, off);
  }
  float tau = (fs + nU - kf) / fmaxf(nS, 1.f);
  tau = (nS > 0.f) ? tau : tau0;
  float* mo = mu + (size_t)pid*512;
  #pragma unroll
  for (int i = 0; i < 8; ++i) mo[i*64 + lane] = fminf(fmaxf(v[i]-tau, 0.f), 1.f);
}

// -------- hp[b,head,e] = sum_s mu * h --------
__global__ __launch_bounds__(512) void k_hp(
    const float* __restrict__ mu, const float* __restrict__ hf,
    const float* __restrict__ hb, float* __restrict__ hp)
{
  __shared__ float mul[512];
  int pid = blockIdx.x, b = pid >> 2;
  int t = threadIdx.x;
  mul[t] = mu[(size_t)pid*512 + t];
  __syncthreads();
  if (t < ENC_) {
    const float* hsrc = (t < H_) ? (hf + t) : (hb + (t - H_));
    float acc = 0.f;
    for (int s = 0; s < 512; ++s) {
      float m = mul[s];
      if (m != 0.f) acc += m * hsrc[((size_t)b*S_ + s)*H_];
    }
    hp[(size_t)pid*ENC_ + t] = acc;
  }
}

// -------- head --------
__global__ __launch_bounds__(512) void k_head(
    const float* __restrict__ hp, const float* __restrict__ Wv,
    const float* __restrict__ Wout, const float* __restrict__ Wh,
    const float* __restrict__ bh, float* __restrict__ out)
{
  __shared__ float hpl[1600];
  __shared__ float ppl[ENC_];
  __shared__ float ojl[ENC_];
  __shared__ float red[512];
  int b = blockIdx.x, t = threadIdx.x;
  for (int i = t; i < 1600; i += 512) hpl[i] = hp[(size_t)b*1600 + i];
  __syncthreads();
  if (t < ENC_) {
    int head = t / 100;
    float acc = 0.f;
    for (int e = 0; e < ENC_; ++e) acc += hpl[head*ENC_ + e] * Wv[(size_t)e*ENC_ + t];
    ppl[t] = acc;
  }
  __syncthreads();
  if (t < ENC_) {
    float acc = 0.f;
    for (int c = 0; c < ENC_; ++c) acc += ppl[c] * Wout[(size_t)c*ENC_ + t];
    ojl[t] = acc;
  }
  __syncthreads();
  red[t] = (t < ENC_) ? ojl[t]*Wh[t] : 0.f;
  __syncthreads();
  for (int sft = 256; sft; sft >>= 1) {
    if (t < sft) red[t] += red[t+sft];
    __syncthreads();
  }
  if (t == 0) out[b] = 1.f/(1.f + expf(-(red[0] + bh[0])));
}

// -------- z --------
__global__ void k_z(const float* __restrict__ mu, const int* __restrict__ lengths,
                    float* __restrict__ out) {
  int idx = blockIdx.x*256 + threadIdx.x;
  int b = idx >> 9, s = idx & 511;
  float zz = 0.f;
  if (s < lengths[b]) {
    size_t base = (size_t)b*2048 + s;
    zz = 0.25f*(mu[base] + mu[base+512] + mu[base+1024] + mu[base+1536]);
  }
  out[32 + idx] = zz;
}

extern "C" void kernel_launch(void* const* d_in, const int* in_sizes, int n_in,
                              void* d_out, int out_size, void* d_ws, size_t ws_size,
                              hipStream_t stream) {
  const int*   x    = (const int*)d_in[0];
  const void*  mask = d_in[1];
  const float* emb  = (const float*)d_in[2];
  const float* wihf = (const float*)d_in[3];
  const float* whhf = (const float*)d_in[4];
  const float* bf   = (const float*)d_in[5];
  const float* wihb = (const float*)d_in[6];
  const float* whhb = (const float*)d_in[7];
  const float* bb   = (const float*)d_in[8];
  const float* qs   = (const float*)d_in[9];
  const float* Wq   = (const float*)d_in[10];
  const float* Wk   = (const float*)d_in[11];
  const float* Wv   = (const float*)d_in[12];
  const float* Wout = (const float*)d_in[13];
  const float* Wh   = (const float*)d_in[14];
  const float* bh   = (const float*)d_in[15];
  float* out = (float*)d_out;
  float* W = (float*)d_ws;
  int* lengths = (int*)(W + OF_LEN);

  // Gate: use v2b only if truly spill-free (pins honored, no scratch).
  // Host-only query, deterministic, graph-capture-safe.
  hipFuncAttributes fa{};
  bool use_v2b = false;
  if (hipFuncGetAttributes(&fa, (const void*)k_lstm_v2b) == hipSuccess)
    use_v2b = (fa.localSizeBytes <= 32);

  k_lengths<<<32, 64, 0, stream>>>(mask, lengths);
  k_qvec<<<1, 512, 0, stream>>>(qs, Wq, W+OF_QVEC);
  k_wkq<<<7, 256, 0, stream>>>(Wk, W+OF_QVEC, W+OF_WKQ);
  k_gemm_mfma<<<dim3(128, 25), 256, 0, stream>>>(x, emb, wihf, wihb, bf, bb,
                                                 W+OF_XWF, W+OF_XWB);
  if (use_v2b)
    k_lstm_v2b<<<64, 512, 0, stream>>>(W+OF_XWF, W+OF_XWB, whhf, whhb,
                                       lengths, W+OF_HF, W+OF_HB);
  else
    k_lstm_v2<<<64, 1024, 0, stream>>>(W+OF_XWF, W+OF_XWB, whhf, whhb,
                                       lengths, W+OF_HF, W+OF_HB);
  k_scores<<<4096, 256, 0, stream>>>(W+OF_HF, W+OF_HB, W+OF_WKQ, lengths, W+OF_THETA);
  k_sparsemap<<<128, 64, 0, stream>>>(W+OF_THETA, lengths, W+OF_MU);
  k_hp<<<128, 512, 0, stream>>>(W+OF_MU, W+OF_HF, W+OF_HB, W+OF_HP);
  k_head<<<32, 512, 0, stream>>>(W+OF_HP, Wv, Wout, Wh, bh, out);
  k_z<<<64, 256, 0, stream>>>(W+OF_MU, lengths, out);
}